// Round 7
// baseline (23.468 us; speedup 1.0000x reference)
//
#include <hip/hip_runtime.h>
#include <math.h>

#define TPB 1024
#define WAVES 16
#define RAYS_PB 256      // rays per block
#define RPT 4            // rays per thread (RAYS_PB / 64)
#define MAXPTS 2048      // points staged in LDS per chunk (32 KB as float4)

// ---------------------------------------------------------------------------
// Fused main: grid = (ceil(M/256), B), block = 1024 (16 waves, 4/SIMD).
// Each block: 256 rays vs ALL N points.
//  - stages pc directly into LDS as (qx,qy,qz,-0.5|q|^2)
//  - computes the COMPLETE maxdist locally
//  - wave w scans its N/16 point chunk for all 256 rays (4 rays/thread in
//    registers; each broadcast ds_read_b128 amortized over 4 rays);
//    2 points/iter -> v_max3 fusion for the running max
//  - cross-wave max combine in LDS, masked sum -> ONE float2 per block.
// Fully deterministic: fixed-order in-block reductions, no atomics.
//   min_n d2 = pn - 2 * max_n (p.q - 0.5|q|^2),  q.w = -0.5|q|^2
// ---------------------------------------------------------------------------
__global__ __launch_bounds__(TPB) void chamfer_main(
    const float* __restrict__ c, const float* __restrict__ depth,
    const float* __restrict__ pc, float2* __restrict__ partial,
    int res, int M, int N)
{
    __shared__ float4 spts[MAXPTS];           // 32 KB
    __shared__ float red[WAVES][RAYS_PB];     // 16 KB
    __shared__ float smax[WAVES];
    __shared__ float bs[RPT], bc[RPT];

    int tile = blockIdx.x, b = blockIdx.y;
    int tid = threadIdx.x, w = tid >> 6, lane = tid & 63;

    const float* cb = c + b * 25;
    float fx = cb[16], sk = cb[17], cx = cb[18];
    float fy = cb[20], cy = cb[21];
    float ox = cb[3], oy = cb[7], oz = cb[11];

    // ---- ray setup: 4 rays per thread (every wave holds all 256 rays) ----
    float px[RPT], py[RPT], pz[RPT], pn[RPT], dep[RPT], mxs[RPT];
    #pragma unroll
    for (int r = 0; r < RPT; ++r) {
        int m = tile * RAYS_PB + lane + 64 * r;
        int mm = min(m, M - 1);
        int i = mm / res, j = mm - i * res;
        float x = (j + 0.5f) / (float)res;
        float y = (i + 0.5f) / (float)res;
        float xl = (x - cx + cy * sk / fy - sk * y / fy) / fx;
        float yl = (y - cy) / fy;
        float wx = cb[0] * xl + cb[1] * yl + cb[2] + cb[3];
        float wy = cb[4] * xl + cb[5] * yl + cb[6] + cb[7];
        float wz = cb[8] * xl + cb[9] * yl + cb[10] + cb[11];
        float dx = wx - ox, dy = wy - oy, dz = wz - oz;
        float nrm = fmaxf(sqrtf(dx * dx + dy * dy + dz * dz), 1e-12f);
        dx /= nrm; dy /= nrm; dz /= nrm;
        float d = depth[(size_t)b * M + mm];
        dep[r] = d;
        px[r] = fmaf(d, dx, ox);
        py[r] = fmaf(d, dy, oy);
        pz[r] = fmaf(d, dz, oz);
        pn[r] = px[r] * px[r] + py[r] * py[r] + pz[r] * pz[r];
        mxs[r] = -3.4e38f;
    }

    // ---- stage + scan all N points (chunked; N<=MAXPTS -> single pass) ----
    float mdl = 0.0f;   // squared distances >= 0
    for (int n0 = 0; n0 < N; n0 += MAXPTS) {
        int kc = min(N - n0, MAXPTS);
        if (n0) __syncthreads();   // previous chunk's reads complete
        const float* src = pc + ((size_t)b * N + n0) * 3;
        for (int p = tid; p < kc; p += TPB) {
            float qx = src[3 * p], qy = src[3 * p + 1], qz = src[3 * p + 2];
            float qn = qx * qx + qy * qy + qz * qz;
            spts[p] = make_float4(qx, qy, qz, -0.5f * qn);
            float dx = qx - ox, dy = qy - oy, dz = qz - oz;
            mdl = fmaxf(mdl, dx * dx + dy * dy + dz * dz);
        }
        __syncthreads();

        int cpw = (kc + WAVES - 1) / WAVES;
        int s0 = min(w * cpw, kc);
        int s1 = min(s0 + cpw, kc);
        int k = s0;
        #pragma unroll 4
        for (; k + 1 < s1; k += 2) {
            float4 qa = spts[k];       // wave-uniform broadcast, conflict-free
            float4 qb = spts[k + 1];
            #pragma unroll
            for (int r = 0; r < RPT; ++r) {
                float sa = fmaf(pz[r], qa.z, qa.w);
                sa = fmaf(py[r], qa.y, sa);
                sa = fmaf(px[r], qa.x, sa);
                float sb = fmaf(pz[r], qb.z, qb.w);
                sb = fmaf(py[r], qb.y, sb);
                sb = fmaf(px[r], qb.x, sb);
                mxs[r] = fmaxf(mxs[r], fmaxf(sa, sb));   // -> v_max3_f32
            }
        }
        for (; k < s1; ++k) {
            float4 q = spts[k];
            #pragma unroll
            for (int r = 0; r < RPT; ++r) {
                float s = fmaf(pz[r], q.z, q.w);
                s = fmaf(py[r], q.y, s);
                s = fmaf(px[r], q.x, s);
                mxs[r] = fmaxf(mxs[r], s);
            }
        }
    }

    // ---- per-wave maxdist partial + per-ray max handoff ----
    for (int off = 32; off; off >>= 1) mdl = fmaxf(mdl, __shfl_down(mdl, off));
    if (lane == 0) smax[w] = mdl;
    #pragma unroll
    for (int r = 0; r < RPT; ++r) red[w][lane + 64 * r] = mxs[r];
    __syncthreads();

    // ---- combine: thread tid (<256) owns ray tid ----
    float s = 0.f, cnt = 0.f;
    if (tid < RAYS_PB) {
        float m2 = smax[0];
        #pragma unroll
        for (int ww = 1; ww < WAVES; ++ww) m2 = fmaxf(m2, smax[ww]);
        float thr = sqrtf(m2);

        float mx = red[0][tid];
        #pragma unroll
        for (int ww = 1; ww < WAVES; ++ww) mx = fmaxf(mx, red[ww][tid]);
        // ray tid's pn/dep live in this thread's slot r == w (static select)
        float pnk = pn[0], dk = dep[0];
        #pragma unroll
        for (int r = 1; r < RPT; ++r) if (w == r) { pnk = pn[r]; dk = dep[r]; }
        int m = tile * RAYS_PB + tid;
        if (m < M) {
            float md = fmaxf(fmaf(-2.0f, mx, pnk), 0.0f);
            if (dk < thr) { s = md; cnt = 1.0f; }
        }
    }
    for (int off = 32; off; off >>= 1) {
        s += __shfl_down(s, off);
        cnt += __shfl_down(cnt, off);
    }
    if (tid < RAYS_PB && lane == 0) { bs[w] = s; bc[w] = cnt; }
    __syncthreads();
    if (tid == 0) {
        float S = 0.f, C = 0.f;
        #pragma unroll
        for (int ww = 0; ww < RPT; ++ww) { S += bs[ww]; C += bc[ww]; }
        partial[(size_t)b * gridDim.x + blockIdx.x] = make_float2(S, C);
    }
}

// ---------------------------------------------------------------------------
// Finalize: ONE block; wave w reduces batch w's ntiles partials.
// ---------------------------------------------------------------------------
__global__ __launch_bounds__(1024) void finalize_kernel(
    const float2* __restrict__ partial, float* __restrict__ out,
    int ntiles, int B)
{
    int w = threadIdx.x >> 6, lane = threadIdx.x & 63;
    if (w >= B) return;
    float S = 0.f, C = 0.f;
    for (int i = lane; i < ntiles; i += 64) {
        float2 p = partial[(size_t)w * ntiles + i];
        S += p.x; C += p.y;
    }
    for (int off = 32; off; off >>= 1) {
        S += __shfl_down(S, off);
        C += __shfl_down(C, off);
    }
    if (lane == 0) out[w] = S / fmaxf(C, 1.0f);
}

extern "C" void kernel_launch(void* const* d_in, const int* in_sizes, int n_in,
                              void* d_out, int out_size, void* d_ws, size_t ws_size,
                              hipStream_t stream) {
    const float* c     = (const float*)d_in[0];
    const float* depth = (const float*)d_in[1];
    const float* pc    = (const float*)d_in[2];

    int B = in_sizes[0] / 25;
    int M = in_sizes[1] / B;
    int N = in_sizes[2] / (3 * B);
    int res = 1;
    while (res * res < M) ++res;

    float2* partial = (float2*)d_ws;

    int ntiles = (M + RAYS_PB - 1) / RAYS_PB;

    chamfer_main<<<dim3(ntiles, B), TPB, 0, stream>>>(c, depth, pc, partial,
                                                      res, M, N);
    finalize_kernel<<<1, B * 64, 0, stream>>>(partial, (float*)d_out,
                                              ntiles, B);
}